// Round 6
// baseline (370.060 us; speedup 1.0000x reference)
//
#include <hip/hip_runtime.h>
#include <stdint.h>
#include <math.h>

#define NB 8
#define NN 4096
#define ND 64

__host__ __device__ __forceinline__ uint32_t rotl32(uint32_t x, uint32_t d) {
#ifdef __HIP_DEVICE_COMPILE__
  return __builtin_amdgcn_alignbit(x, x, 32u - d);   // v_alignbit_b32: 1 inst
#else
  return (x << d) | (x >> (32u - d));
#endif
}

// JAX threefry2x32: 20 rounds, rotations (13,15,26,6),(17,29,16,24)
__host__ __device__ __forceinline__ void tf2x32(uint32_t k0, uint32_t k1,
                                                uint32_t& x0, uint32_t& x1) {
  const uint32_t ks2 = k0 ^ k1 ^ 0x1BD11BDAu;
  x0 += k0; x1 += k1;
#define TF_R(r) { x0 += x1; x1 = rotl32(x1, r); x1 ^= x0; }
  TF_R(13u) TF_R(15u) TF_R(26u) TF_R(6u)
  x0 += k1;  x1 += ks2 + 1u;
  TF_R(17u) TF_R(29u) TF_R(16u) TF_R(24u)
  x0 += ks2; x1 += k0 + 2u;
  TF_R(13u) TF_R(15u) TF_R(26u) TF_R(6u)
  x0 += k0;  x1 += k1 + 3u;
  TF_R(17u) TF_R(29u) TF_R(16u) TF_R(24u)
  x0 += k1;  x1 += ks2 + 4u;
  TF_R(13u) TF_R(15u) TF_R(26u) TF_R(6u)
  x0 += ks2; x1 += k0 + 5u;
#undef TF_R
}

// uniform[tiny,1) from 32 random bits (partitionable threefry: bits = out0^out1)
__device__ __forceinline__ float unif_from_bits(uint32_t bits) {
  const float tiny = 1.1754943508222875e-38f;
  uint32_t fb = (bits >> 9) | 0x3f800000u;
  float f = __uint_as_float(fb) - 1.0f;      // [0,1)
  return fmaxf(tiny, f + tiny);
}

// Exact (f64-rounded-to-f32) gumbel — must match the passing R2-R5 semantics.
__device__ __forceinline__ float gumbel_exact(uint32_t bits) {
  float u = unif_from_bits(bits);
  float w = (float)(-log((double)u));        // -log(u), f32-rounded
  float g = (float)(-log((double)w));        // -log(w), f32-rounded
  return g;
}

// c2[b,j] = -ln2 * exp(-w[b,j])  (screen-key table; sign folds log2 -> -log)
__global__ __launch_bounds__(256)
void expw_kernel(const float* __restrict__ weight, float* __restrict__ c2) {
  int i = blockIdx.x * 256 + threadIdx.x;    // 0 .. 32767
  c2[i] = -0.69314718055994530942f * __expf(-weight[i]);
}

// One 128-thread block per output row (b,i), 32 elements/thread, processed as
// 4 explicitly-interleaved threefry chains (ILP: threefry is a serial 70-op
// ARX chain; 4 chains in flight cover the ~4-cycle VALU dependent latency).
// Phase 1: a_j = log2(f_j) * c2_j (hw v_log_f32); per-thread top-2 minima.
// Phase 2: exact re-eval (f64 logs, f32 g+w key, first-index tie-break) of
//          candidates within 0.2% of the approx min (>> hw log error).
__global__ __launch_bounds__(128)
void cat_kernel(const float* __restrict__ weight, const float* __restrict__ c2,
                int* __restrict__ idx_out, uint32_t k0, uint32_t k1) {
  int row = blockIdx.x;                 // b*NN + i, 0..32767
  int b = row >> 12;
  uint32_t base = (uint32_t)row << 12;  // row * NN
  const float* crow = c2 + (b << 12);
  const float* wrow = weight + (b << 12);
  int t = threadIdx.x;

  const uint32_t ks2 = k0 ^ k1 ^ 0x1BD11BDAu;
  const uint32_t s1 = base + k1;        // fold counter base + key inject
  const uint32_t cA = ks2 + 1u, cB = k0 + 2u, cC = k1 + 3u, cD = ks2 + 4u, cE = k0 + 5u;

  float v1 = INFINITY, v2 = INFINITY;
  int i1 = 0, i2 = 0;

#define TF4_R(r) \
  ya0 += ya1; yb0 += yb1; yc0 += yc1; yd0 += yd1; \
  ya1 = rotl32(ya1, r); yb1 = rotl32(yb1, r); yc1 = rotl32(yc1, r); yd1 = rotl32(yd1, r); \
  ya1 ^= ya0; yb1 ^= yb0; yc1 ^= yc0; yd1 ^= yd0;
#define TF4_INJ(p, q) \
  ya0 += (p); yb0 += (p); yc0 += (p); yd0 += (p); \
  ya1 += (q); yb1 += (q); yc1 += (q); yd1 += (q);

  for (int it = 0; it < 8; ++it) {
    int j0 = t + it * 512;              // chains at j0, j0+128, j0+256, j0+384
    uint32_t ya0 = k0, ya1 = s1 + (uint32_t)j0;
    uint32_t yb0 = k0, yb1 = ya1 + 128u;
    uint32_t yc0 = k0, yc1 = ya1 + 256u;
    uint32_t yd0 = k0, yd1 = ya1 + 384u;
    TF4_R(13u) TF4_R(15u) TF4_R(26u) TF4_R(6u)
    TF4_INJ(k1, cA)
    TF4_R(17u) TF4_R(29u) TF4_R(16u) TF4_R(24u)
    TF4_INJ(ks2, cB)
    TF4_R(13u) TF4_R(15u) TF4_R(26u) TF4_R(6u)
    TF4_INJ(k0, cC)
    TF4_R(17u) TF4_R(29u) TF4_R(16u) TF4_R(24u)
    TF4_INJ(k1, cD)
    TF4_R(13u) TF4_R(15u) TF4_R(26u) TF4_R(6u)
    TF4_INJ(ks2, cE)

    float fa = __uint_as_float((((ya0 ^ ya1) >> 9)) | 0x3f800000u) - 1.0f;
    float fb = __uint_as_float((((yb0 ^ yb1) >> 9)) | 0x3f800000u) - 1.0f;
    float fc = __uint_as_float((((yc0 ^ yc1) >> 9)) | 0x3f800000u) - 1.0f;
    float fd = __uint_as_float((((yd0 ^ yd1) >> 9)) | 0x3f800000u) - 1.0f;
    float aa = __log2f(fa) * crow[j0];
    float ab = __log2f(fb) * crow[j0 + 128];
    float ac = __log2f(fc) * crow[j0 + 256];
    float ad = __log2f(fd) * crow[j0 + 384];

#define TRACK(aval, jval) \
    if ((aval) < v2) { \
      if ((aval) < v1) { v2 = v1; i2 = i1; v1 = (aval); i1 = (jval); } \
      else             { v2 = (aval); i2 = (jval); } \
    }
    TRACK(aa, j0)
    TRACK(ab, j0 + 128)
    TRACK(ac, j0 + 256)
    TRACK(ad, j0 + 384)
#undef TRACK
  }
#undef TF4_R
#undef TF4_INJ

  // wave-level min of v1, then cross-wave via 2-slot LDS
  float m = v1;
  #pragma unroll
  for (int off = 1; off < 64; off <<= 1) m = fminf(m, __shfl_xor(m, off));
  __shared__ float wmin[2];
  __shared__ int cnt;
  __shared__ float ckey[16];
  __shared__ int cidx[16];
  int lane = t & 63, wid = t >> 6;
  if (t == 0) cnt = 0;
  if (lane == 0) wmin[wid] = m;
  __syncthreads();
  float thr = fminf(wmin[0], wmin[1]) * 1.002f;

  #pragma unroll
  for (int c = 0; c < 2; ++c) {
    float v = c ? v2 : v1;
    int j   = c ? i2 : i1;
    if (v <= thr) {
      uint32_t x0 = 0u, x1 = base + (uint32_t)j;
      tf2x32(k0, k1, x0, x1);
      float key = gumbel_exact(x0 ^ x1) + wrow[j];
      int slot = atomicAdd(&cnt, 1);
      if (slot < 16) { ckey[slot] = key; cidx[slot] = j; }
    }
  }
  __syncthreads();
  if (t == 0) {
    int n = cnt < 16 ? cnt : 16;
    float bk = -INFINITY; int bj = 0x7fffffff;
    for (int q = 0; q < n; ++q) {
      float kq = ckey[q]; int jq = cidx[q];
      if (kq > bk || (kq == bk && jq < bj)) { bk = kq; bj = jq; }
    }
    idx_out[row] = bj;
  }
}

// new_state[b,i,d] = state[b, idx[b,i], d] + 0.1 * sqrt(2)*erfinv(u)
// new_weight = 0 (density - stop_gradient(density) is identically zero fwd).
__global__ __launch_bounds__(256)
void sample_kernel(const float* __restrict__ state, const int* __restrict__ idx,
                   float* __restrict__ out_state, float* __restrict__ out_w,
                   uint32_t k0, uint32_t k1) {
  uint32_t e = (uint32_t)(blockIdx.x * 256 + threadIdx.x);  // 0 .. 2097151
  uint32_t x0 = 0u, x1 = e;
  tf2x32(k0, k1, x0, x1);
  uint32_t bits = x0 ^ x1;

  const float lo = -0.9999999403953552f;     // nextafter(-1, 0)
  uint32_t fb = (bits >> 9) | 0x3f800000u;
  float f = __uint_as_float(fb) - 1.0f;      // [0,1)
  float u = fmaxf(lo, fmaf(f, 2.0f, lo));    // f*(hi-lo)+lo, hi-lo==2.0f (exact mul)
  float nz = 1.41421356237f * erfinvf(u);

  uint32_t bi = e >> 6;          // b*NN + i
  uint32_t d  = e & 63u;
  uint32_t b  = bi >> 12;
  int anc = idx[bi];
  float a = state[((size_t)b * NN + (size_t)anc) * ND + d];
  out_state[e] = fmaf(0.1f, nz, a);
  if (d == 0) out_w[bi] = 0.0f;
}

extern "C" void kernel_launch(void* const* d_in, const int* in_sizes, int n_in,
                              void* d_out, int out_size, void* d_ws, size_t ws_size,
                              hipStream_t stream) {
  const float* state  = (const float*)d_in[0];
  const float* weight = (const float*)d_in[1];
  float* out_state = (float*)d_out;
  float* out_w     = (float*)d_out + (size_t)NB * NN * ND;
  int*   idx_ws = (int*)d_ws;                          // 32768 ints  = 128 KiB
  float* c2     = (float*)d_ws + NB * NN;              // 32768 float = 128 KiB

  // jax.random.key(42) -> [0,42]; partitionable split (foldlike):
  // child key i = full output block of threefry((0,42), counter=(0,i))
  uint32_t a0 = 0u, a1 = 0u; tf2x32(0u, 42u, a0, a1);  // counter (0,0) -> k_idx
  uint32_t b0 = 0u, b1 = 1u; tf2x32(0u, 42u, b0, b1);  // counter (0,1) -> k_noise

  hipLaunchKernelGGL(expw_kernel, dim3(NB * NN / 256), dim3(256), 0, stream,
                     weight, c2);
  hipLaunchKernelGGL(cat_kernel, dim3(NB * NN), dim3(128), 0, stream,
                     weight, c2, idx_ws, a0, a1);
  hipLaunchKernelGGL(sample_kernel, dim3((NB * NN * ND) / 256), dim3(256), 0, stream,
                     state, idx_ws, out_state, out_w, b0, b1);
}

// Round 7
// 285.533 us; speedup vs baseline: 1.2960x; 1.2960x over previous
//
#include <hip/hip_runtime.h>
#include <stdint.h>
#include <math.h>

#define NB 8
#define NN 4096
#define ND 64

__host__ __device__ __forceinline__ uint32_t rotl32(uint32_t x, uint32_t d) {
#ifdef __HIP_DEVICE_COMPILE__
  return __builtin_amdgcn_alignbit(x, x, 32u - d);   // v_alignbit_b32: 1 inst
#else
  return (x << d) | (x >> (32u - d));
#endif
}

// JAX threefry2x32: 20 rounds, rotations (13,15,26,6),(17,29,16,24)
__host__ __device__ __forceinline__ void tf2x32(uint32_t k0, uint32_t k1,
                                                uint32_t& x0, uint32_t& x1) {
  const uint32_t ks2 = k0 ^ k1 ^ 0x1BD11BDAu;
  x0 += k0; x1 += k1;
#define TF_R(r) { x0 += x1; x1 = rotl32(x1, r); x1 ^= x0; }
  TF_R(13u) TF_R(15u) TF_R(26u) TF_R(6u)
  x0 += k1;  x1 += ks2 + 1u;
  TF_R(17u) TF_R(29u) TF_R(16u) TF_R(24u)
  x0 += ks2; x1 += k0 + 2u;
  TF_R(13u) TF_R(15u) TF_R(26u) TF_R(6u)
  x0 += k0;  x1 += k1 + 3u;
  TF_R(17u) TF_R(29u) TF_R(16u) TF_R(24u)
  x0 += k1;  x1 += ks2 + 4u;
  TF_R(13u) TF_R(15u) TF_R(26u) TF_R(6u)
  x0 += ks2; x1 += k0 + 5u;
#undef TF_R
}

// f_bits = 0x3f800000 | (bits >> 9)  in one v_alignbit_b32
__device__ __forceinline__ uint32_t mant_bits(uint32_t bits) {
  return __builtin_amdgcn_alignbit(127u, bits, 9u);   // (127<<23)|(bits>>9)
}

// uniform[tiny,1) from 32 random bits (partitionable threefry: bits = out0^out1)
__device__ __forceinline__ float unif_from_bits(uint32_t bits) {
  const float tiny = 1.1754943508222875e-38f;
  float f = __uint_as_float(mant_bits(bits)) - 1.0f;   // [0,1)
  return fmaxf(tiny, f + tiny);
}

// Exact (f64-rounded-to-f32) gumbel — must match the passing R2-R6 semantics.
__device__ __forceinline__ float gumbel_exact(uint32_t bits) {
  float u = unif_from_bits(bits);
  float w = (float)(-log((double)u));        // -log(u), f32-rounded
  float g = (float)(-log((double)w));        // -log(w), f32-rounded
  return g;
}

// c2[b,j] = -ln2 * exp(-w[b,j])  (screen-key table; sign folds log2 -> -log)
__global__ __launch_bounds__(256)
void expw_kernel(const float* __restrict__ weight, float* __restrict__ c2) {
  int i = blockIdx.x * 256 + threadIdx.x;    // 0 .. 32767
  c2[i] = -0.69314718055994530942f * __expf(-weight[i]);
}

// One 128-thread block per output row (b,i), 32 elements/thread.
// Phase 1: a_j = log2(f_j) * c2_j (hw v_log_f32), packed key
//          pa = (bits(a_j) & 0xFFFFF000) | j  (a_j>0 => unsigned-monotone);
//          per-thread top-2 packed minima via v_min_u32/v_max_u32.
//          argmin a_j == argmax gumbel_j + w_j (monotone transform).
// Phase 2: exact re-eval (f64 logs, f32 g+w key, first-index tie-break) of
//          candidates within 0.6% of the approx min (covers hw log error
//          ~1e-6 rel + key truncation 2^-11 rel).
__global__ __launch_bounds__(128)
void cat_kernel(const float* __restrict__ weight, const float* __restrict__ c2,
                int* __restrict__ idx_out, uint32_t k0, uint32_t k1) {
  int row = blockIdx.x;                 // b*NN + i, 0..32767
  int b = row >> 12;
  uint32_t base = (uint32_t)row << 12;  // row * NN
  const float* crow = c2 + (b << 12);
  const float* wrow = weight + (b << 12);
  int t = threadIdx.x;

  uint32_t pk1 = 0xFFFFFFFFu, pk2 = 0xFFFFFFFFu;
  #pragma unroll 8
  for (int j = t; j < NN; j += 128) {
    uint32_t x0 = 0u, x1 = base + (uint32_t)j;
    tf2x32(k0, k1, x0, x1);
    uint32_t bits = x0 ^ x1;
    float f = __uint_as_float(mant_bits(bits)) - 1.0f;  // [0,1)
    float a = __log2f(f) * crow[j];     // >0 finite (or +inf if f==0: excluded)
    uint32_t pa = (__float_as_uint(a) & 0xFFFFF000u) | (uint32_t)j;
    uint32_t pm = pk1 > pa ? pk1 : pa;  // v_max_u32
    pk1 = pk1 < pa ? pk1 : pa;          // v_min_u32
    pk2 = pk2 < pm ? pk2 : pm;          // v_min_u32
  }

  // wave-level min of pk1 (packed: carries index), then cross-wave via LDS
  uint32_t m = pk1;
  #pragma unroll
  for (int off = 1; off < 64; off <<= 1) {
    uint32_t o = (uint32_t)__shfl_xor((int)m, off);
    m = m < o ? m : o;
  }
  __shared__ uint32_t wmin[2];
  __shared__ int cnt;
  __shared__ float ckey[16];
  __shared__ int cidx[16];
  int lane = t & 63, wid = t >> 6;
  if (t == 0) cnt = 0;
  if (lane == 0) wmin[wid] = m;
  __syncthreads();
  uint32_t gmin = wmin[0] < wmin[1] ? wmin[0] : wmin[1];
  // threshold on truncated keys; global-min element always passes (thr >= its key)
  float thr = __uint_as_float(gmin & 0xFFFFF000u) * 1.006f;

  #pragma unroll
  for (int c = 0; c < 2; ++c) {
    uint32_t pk = c ? pk2 : pk1;
    float cf = __uint_as_float(pk & 0xFFFFF000u);   // NaN if pk untouched -> fails <=
    if (cf <= thr) {
      int j = (int)(pk & 0xFFFu);
      uint32_t x0 = 0u, x1 = base + (uint32_t)j;
      tf2x32(k0, k1, x0, x1);
      float key = gumbel_exact(x0 ^ x1) + wrow[j];
      int slot = atomicAdd(&cnt, 1);
      if (slot < 16) { ckey[slot] = key; cidx[slot] = j; }
    }
  }
  __syncthreads();
  if (t == 0) {
    int n = cnt < 16 ? cnt : 16;
    float bk = -INFINITY; int bj = 0x7fffffff;
    for (int q = 0; q < n; ++q) {
      float kq = ckey[q]; int jq = cidx[q];
      if (kq > bk || (kq == bk && jq < bj)) { bk = kq; bj = jq; }
    }
    idx_out[row] = bj;
  }
}

// new_state[b,i,d] = state[b, idx[b,i], d] + 0.1 * sqrt(2)*erfinv(u)
// new_weight = 0 (density - stop_gradient(density) is identically zero fwd).
__global__ __launch_bounds__(256)
void sample_kernel(const float* __restrict__ state, const int* __restrict__ idx,
                   float* __restrict__ out_state, float* __restrict__ out_w,
                   uint32_t k0, uint32_t k1) {
  uint32_t e = (uint32_t)(blockIdx.x * 256 + threadIdx.x);  // 0 .. 2097151
  uint32_t x0 = 0u, x1 = e;
  tf2x32(k0, k1, x0, x1);
  uint32_t bits = x0 ^ x1;

  const float lo = -0.9999999403953552f;     // nextafter(-1, 0)
  float f = __uint_as_float(mant_bits(bits)) - 1.0f;  // [0,1)
  float u = fmaxf(lo, fmaf(f, 2.0f, lo));    // f*(hi-lo)+lo, hi-lo==2.0f (exact mul)
  float nz = 1.41421356237f * erfinvf(u);

  uint32_t bi = e >> 6;          // b*NN + i
  uint32_t d  = e & 63u;
  uint32_t b  = bi >> 12;
  int anc = idx[bi];
  float a = state[((size_t)b * NN + (size_t)anc) * ND + d];
  out_state[e] = fmaf(0.1f, nz, a);
  if (d == 0) out_w[bi] = 0.0f;
}

extern "C" void kernel_launch(void* const* d_in, const int* in_sizes, int n_in,
                              void* d_out, int out_size, void* d_ws, size_t ws_size,
                              hipStream_t stream) {
  const float* state  = (const float*)d_in[0];
  const float* weight = (const float*)d_in[1];
  float* out_state = (float*)d_out;
  float* out_w     = (float*)d_out + (size_t)NB * NN * ND;
  int*   idx_ws = (int*)d_ws;                          // 32768 ints  = 128 KiB
  float* c2     = (float*)d_ws + NB * NN;              // 32768 float = 128 KiB

  // jax.random.key(42) -> [0,42]; partitionable split (foldlike):
  // child key i = full output block of threefry((0,42), counter=(0,i))
  uint32_t a0 = 0u, a1 = 0u; tf2x32(0u, 42u, a0, a1);  // counter (0,0) -> k_idx
  uint32_t b0 = 0u, b1 = 1u; tf2x32(0u, 42u, b0, b1);  // counter (0,1) -> k_noise

  hipLaunchKernelGGL(expw_kernel, dim3(NB * NN / 256), dim3(256), 0, stream,
                     weight, c2);
  hipLaunchKernelGGL(cat_kernel, dim3(NB * NN), dim3(128), 0, stream,
                     weight, c2, idx_ws, a0, a1);
  hipLaunchKernelGGL(sample_kernel, dim3((NB * NN * ND) / 256), dim3(256), 0, stream,
                     state, idx_ws, out_state, out_w, b0, b1);
}